// Round 5
// baseline (187.435 us; speedup 1.0000x reference)
//
#include <hip/hip_runtime.h>

// Involution (B=8, H=W=192, C=64, G=4, K=3, R=4) — round 9: KERNEL SPLIT.
// R8 post-mortem: mask 0x107 let regalloc REMATERIALIZE ring loads
// (VGPR 80, FETCH 56->67MB) — sched_barrier doesn't bind regalloc.
// R6 (mask 0) stays the proven Phase-B. Across R4-R8 the counters agree:
// VALU<26%, HBM<26%, occ<32% -> issue-structure limited (~2 TB/s on
// 145MB real traffic; need ~2.8MB outstanding for 6.3 TB/s, each wave
// holds <=4.5KB and only in Phase-B windows). Phase A is a 3200-cyc
// VALU region with ZERO memory in flight, lockstepping both waves via
// the barrier — structural dead time.
// R9: split. gen_kern streams x->kern(ws) with no LDS/barrier at high
// occupancy; apply_kern stages kern tile (9 coalesced loads, one
// latency) then runs R6's phase_b VERBATIM (mask-0 fences, 4-slot ring).
// +85MB ws traffic (floor 21->34us) traded for continuous MLP.
// Fallback to exact-R6 fused if ws_size < 42.5MB (host branch on a
// capture-constant -> graph-safe).
// GATE: gen ~15-25us / apply ~45-60us, sum <= 75us. If sum >= fused,
// structure wasn't the limiter -> investigate raw BW next.

#define B_   8
#define H_   192
#define W_   192
#define CR_  16
#define TH_  8
#define TW_  16
#define TILES_X (W_/TW_)                    // 12
#define TILES_PER_IMG (TILES_X*(H_/TH_))    // 288
#define NBLK (B_*TILES_PER_IMG)             // 2304
#define NPIX (TH_*TW_)                      // 128
#define NPIX_TOT (B_*H_*W_)                 // 294912
#define WS_NEED ((size_t)NPIX_TOT * 36 * 4) // 42.47 MB

constexpr float BN_EPS = 1e-3f;

__device__ __forceinline__ float4 mask4(float4 k, bool v) {
    k.x = v ? k.x : 0.f;
    k.y = v ? k.y : 0.f;
    k.z = v ? k.z : 0.f;
    k.w = v ? k.w : 0.f;
    return k;
}

__device__ __forceinline__ void fma4(float4& a, const float4 k, const float4 x) {
    a.x = fmaf(k.x, x.x, a.x);
    a.y = fmaf(k.y, x.y, a.y);
    a.z = fmaf(k.z, x.z, a.z);
    a.w = fmaf(k.w, x.w, a.w);
}

// ---- shared kern-generation math (identical numerics in both paths) ----
__device__ __forceinline__ void kern_math(const float4* __restrict__ xp,
                                          const float* __restrict__ w1,
                                          const float* __restrict__ b1,
                                          const float* __restrict__ gamma,
                                          const float* __restrict__ beta,
                                          const float* __restrict__ mean,
                                          const float* __restrict__ var,
                                          const float* __restrict__ w2,
                                          const float* __restrict__ b2,
                                          float (&ke)[36])
{
    float td[CR_];
    #pragma unroll
    for (int d = 0; d < CR_; ++d) td[d] = 0.f;

    // t = x @ w1   (weight addresses wave-uniform -> s_load, SMEM pipe)
    #pragma unroll
    for (int c4 = 0; c4 < 16; ++c4) {
        const float4 xv = xp[c4];
        const float xs[4] = {xv.x, xv.y, xv.z, xv.w};
        #pragma unroll
        for (int k = 0; k < 4; ++k) {
            const float* wr = w1 + (c4 * 4 + k) * CR_;
            #pragma unroll
            for (int d = 0; d < CR_; ++d)
                td[d] = fmaf(xs[k], wr[d], td[d]);
        }
    }

    // + b1, BN (inference), ReLU — folded affine
    #pragma unroll
    for (int d = 0; d < CR_; ++d) {
        const float a = gamma[d] * rsqrtf(var[d] + BN_EPS);
        const float c = (b1[d] - mean[d]) * a + beta[d];
        td[d] = fmaxf(fmaf(td[d], a, c), 0.f);
    }

    // kern = t @ w2 + b2  (e = tap*4 + g)
    #pragma unroll
    for (int e = 0; e < 36; ++e) ke[e] = b2[e];
    #pragma unroll
    for (int d = 0; d < CR_; ++d) {
        const float t = td[d];
        const float* wr = w2 + d * 36;
        #pragma unroll
        for (int e = 0; e < 36; ++e)
            ke[e] = fmaf(t, wr[e], ke[e]);
    }
}

// ---- Phase B: R6-proven column-walk (mask-0 fences, 4-slot ring) --------
#define LROWS(S, R)                                                         \
    do {                                                                    \
        int rr_ = (R);                                                      \
        if (!INTERIOR) {                                                    \
            if ((unsigned)rr_ < (unsigned)H_) rv |= (1 << (S));             \
            else                              rv &= ~(1 << (S));            \
            rr_ = rr_ < 0 ? 0 : (rr_ >= H_ ? H_ - 1 : rr_);                 \
        }                                                                   \
        const int rb_ = rr_ * (W_ * 16);                                    \
        rgA[S][0] = x4[rb_ + coA[0]];                                       \
        rgA[S][1] = x4[rb_ + coA[1]];                                       \
        rgA[S][2] = x4[rb_ + coA[2]];                                       \
        rgB[S][0] = x4[rb_ + coB[0]];                                       \
        rgB[S][1] = x4[rb_ + coB[1]];                                       \
        rgB[S][2] = x4[rb_ + coB[2]];                                       \
    } while (0)

#define COMP(I)                                                             \
    do {                                                                    \
        const float4* kqA_ = &s_kern[((I) * TW_ + wslot) * 9];              \
        const float4* kqB_ = &s_kern[((I) * TW_ + wslot + 8) * 9];          \
        float4 aA_ = make_float4(0.f, 0.f, 0.f, 0.f);                       \
        float4 aB_ = make_float4(0.f, 0.f, 0.f, 0.f);                       \
        _Pragma("unroll")                                                   \
        for (int ti_ = 0; ti_ < 3; ++ti_) {                                 \
            const int s_ = ((I) + ti_) & 3;                                 \
            _Pragma("unroll")                                               \
            for (int tj_ = 0; tj_ < 3; ++tj_) {                             \
                float4 kA_ = kqA_[ti_ * 3 + tj_];                           \
                float4 kB_ = kqB_[ti_ * 3 + tj_];                           \
                if (!INTERIOR) {                                            \
                    kA_ = mask4(kA_, (((rv >> s_) & (cmA >> tj_)) & 1));    \
                    kB_ = mask4(kB_, (((rv >> s_) & (cmB >> tj_)) & 1));    \
                }                                                           \
                fma4(aA_, kA_, rgA[s_][tj_]);                               \
                fma4(aB_, kB_, rgB[s_][tj_]);                               \
            }                                                               \
        }                                                                   \
        const int ob_ = (th0 + (I)) * (W_ * 16);                            \
        o4[ob_ + (wA << 4) + c4i] = aA_;                                    \
        o4[ob_ + (wB << 4) + c4i] = aB_;                                    \
    } while (0)

#define SFENCE __builtin_amdgcn_sched_barrier(0)

template <bool INTERIOR>
__device__ __forceinline__ void phase_b(const float4* __restrict__ x4,
                                        float4* __restrict__ o4,
                                        const float4* __restrict__ s_kern,
                                        int th0, int tw0, int tid)
{
    const int wslot = tid >> 4;   // 0..7 -> columns wslot and wslot+8
    const int c4i   = tid & 15;   // float4 channel chunk
    const int wA = tw0 + wslot;
    const int wB = tw0 + wslot + 8;

    int coA[3], coB[3];
    int cmA = 7, cmB = 7;
    #pragma unroll
    for (int tj = 0; tj < 3; ++tj) {
        int wa = wA + tj - 1;
        int wb = wB + tj - 1;
        if (!INTERIOR) {
            if ((unsigned)wa >= (unsigned)W_) cmA &= ~(1 << tj);
            if ((unsigned)wb >= (unsigned)W_) cmB &= ~(1 << tj);
            wa = wa < 0 ? 0 : (wa >= W_ ? W_ - 1 : wa);
            wb = wb < 0 ? 0 : (wb >= W_ ? W_ - 1 : wb);
        }
        coA[tj] = (wa << 4) + c4i;
        coB[tj] = (wb << 4) + c4i;
    }

    float4 rgA[4][3], rgB[4][3];   // 96 VGPR ring, all indices static
    int rv = 0xF;

    LROWS(0, th0 - 1);
    LROWS(1, th0 + 0);
    LROWS(2, th0 + 1);
    LROWS(3, th0 + 2);
    SFENCE;
    COMP(0); LROWS(0, th0 + 3);
    SFENCE;
    COMP(1); LROWS(1, th0 + 4);
    SFENCE;
    COMP(2); LROWS(2, th0 + 5);
    SFENCE;
    COMP(3); LROWS(3, th0 + 6);
    SFENCE;
    COMP(4); LROWS(0, th0 + 7);
    SFENCE;
    COMP(5); LROWS(1, th0 + 8);
    SFENCE;
    COMP(6);
    COMP(7);
}

#undef LROWS
#undef COMP

// ---- split path, kernel A: streaming kern generation (no LDS/barrier) ---
__global__ __launch_bounds__(256, 2)
void gen_kern(const float* __restrict__ x,
              const float* __restrict__ w1,
              const float* __restrict__ b1,
              const float* __restrict__ gamma,
              const float* __restrict__ beta,
              const float* __restrict__ mean,
              const float* __restrict__ var,
              const float* __restrict__ w2,
              const float* __restrict__ b2,
              float* __restrict__ ws)
{
    const int p = blockIdx.x * 256 + threadIdx.x;    // 294912 = 1152*256 exact
    const float4* xp = reinterpret_cast<const float4*>(x) + (size_t)p * 16;

    float ke[36];
    kern_math(xp, w1, b1, gamma, beta, mean, var, w2, b2, ke);

    float4* wp = reinterpret_cast<float4*>(ws) + (size_t)p * 9;
    #pragma unroll
    for (int t9 = 0; t9 < 9; ++t9)
        wp[t9] = make_float4(ke[t9 * 4 + 0], ke[t9 * 4 + 1],
                             ke[t9 * 4 + 2], ke[t9 * 4 + 3]);
}

// ---- split path, kernel B: stage kern tile -> LDS, then R6 phase_b ------
__global__ __launch_bounds__(128, 2)
void apply_kern(const float* __restrict__ x,
                const float* __restrict__ ws,
                float* __restrict__ out)
{
    __shared__ float4 s_kern[NPIX * 9];

    const int bid = blockIdx.x;
    const int img = bid & 7;                 // XCD-aligned image ownership
    const int tin = bid >> 3;
    const int th0 = (tin / TILES_X) * TH_;
    const int tw0 = (tin % TILES_X) * TW_;
    const int tid = threadIdx.x;

    // Stage this tile's kern (9 independent coalesced loads -> one latency,
    // vs the fused kernel's 3200-cycle VALU prefix before the barrier).
    {
        const int r = tid >> 4, cc = tid & 15;
        const size_t gp = (size_t)((img * H_ + th0 + r) * W_ + (tw0 + cc));
        const float4* wp = reinterpret_cast<const float4*>(ws) + gp * 9;
        float4* skq = &s_kern[tid * 9];
        #pragma unroll
        for (int t9 = 0; t9 < 9; ++t9)
            skq[t9] = wp[t9];
    }

    __syncthreads();

    const float4* x4 = reinterpret_cast<const float4*>(x) +
                       (size_t)img * (H_ * W_ * 16);
    float4* o4 = reinterpret_cast<float4*>(out) +
                 (size_t)img * (H_ * W_ * 16);

    const bool interior = (th0 > 0) && (th0 + TH_ < H_) &&
                          (tw0 > 0) && (tw0 + TW_ < W_);
    if (interior)
        phase_b<true >(x4, o4, s_kern, th0, tw0, tid);
    else
        phase_b<false>(x4, o4, s_kern, th0, tw0, tid);
}

// ---- fallback: exact R6 fused kernel (best proven single-kernel) --------
__global__ __launch_bounds__(128, 2)
void invol_fused(const float* __restrict__ x,
                 const float* __restrict__ w1,
                 const float* __restrict__ b1,
                 const float* __restrict__ gamma,
                 const float* __restrict__ beta,
                 const float* __restrict__ mean,
                 const float* __restrict__ var,
                 const float* __restrict__ w2,
                 const float* __restrict__ b2,
                 float* __restrict__ out)
{
    __shared__ float4 s_kern[NPIX * 9];

    const int bid = blockIdx.x;
    const int img = bid & 7;
    const int tin = bid >> 3;
    const int th0 = (tin / TILES_X) * TH_;
    const int tw0 = (tin % TILES_X) * TW_;
    const int tid = threadIdx.x;

    {
        const int r = tid >> 4, cc = tid & 15;
        const int h = th0 + r, w = tw0 + cc;
        const float4* xp = reinterpret_cast<const float4*>(
            x + (((size_t)((img * H_ + h) * W_ + w)) << 6));

        float ke[36];
        kern_math(xp, w1, b1, gamma, beta, mean, var, w2, b2, ke);

        float4* skq = &s_kern[tid * 9];
        #pragma unroll
        for (int t9 = 0; t9 < 9; ++t9)
            skq[t9] = make_float4(ke[t9 * 4 + 0], ke[t9 * 4 + 1],
                                  ke[t9 * 4 + 2], ke[t9 * 4 + 3]);
    }

    __syncthreads();

    const float4* x4 = reinterpret_cast<const float4*>(x) +
                       (size_t)img * (H_ * W_ * 16);
    float4* o4 = reinterpret_cast<float4*>(out) +
                 (size_t)img * (H_ * W_ * 16);

    const bool interior = (th0 > 0) && (th0 + TH_ < H_) &&
                          (tw0 > 0) && (tw0 + TW_ < W_);
    if (interior)
        phase_b<true >(x4, o4, s_kern, th0, tw0, tid);
    else
        phase_b<false>(x4, o4, s_kern, th0, tw0, tid);
}

extern "C" void kernel_launch(void* const* d_in, const int* in_sizes, int n_in,
                              void* d_out, int out_size, void* d_ws, size_t ws_size,
                              hipStream_t stream) {
    const float* x     = (const float*)d_in[0];
    const float* w1    = (const float*)d_in[1];
    const float* b1    = (const float*)d_in[2];
    const float* gamma = (const float*)d_in[3];
    const float* beta  = (const float*)d_in[4];
    const float* mean  = (const float*)d_in[5];
    const float* var   = (const float*)d_in[6];
    const float* w2    = (const float*)d_in[7];
    const float* b2    = (const float*)d_in[8];
    float* out = (float*)d_out;

    if (d_ws != nullptr && ws_size >= WS_NEED) {
        float* ws = (float*)d_ws;
        gen_kern<<<dim3(NPIX_TOT / 256), dim3(256), 0, stream>>>(
            x, w1, b1, gamma, beta, mean, var, w2, b2, ws);
        apply_kern<<<dim3(NBLK), dim3(128), 0, stream>>>(x, ws, out);
    } else {
        invol_fused<<<dim3(NBLK), dim3(128), 0, stream>>>(
            x, w1, b1, gamma, beta, mean, var, w2, b2, out);
    }
}